// Round 1
// baseline (2354.642 us; speedup 1.0000x reference)
//
#include <hip/hip_runtime.h>

#define BB 256
#define TT 1024
#define II 128
#define HH 64
#define GG 256   // 4*HH

// fast sigmoid/tanh via v_exp_f32 + v_rcp_f32 (~1e-6 rel err, fine vs fp32 ref)
__device__ __forceinline__ float fast_sigmoid(float x) {
    return __builtin_amdgcn_rcpf(1.0f + __expf(-x));
}
__device__ __forceinline__ float fast_tanh(float x) {
    // tanh(x) = 1 - 2/(exp(2x)+1); graceful at +-inf (rcp(inf)=0)
    return 1.0f - 2.0f * __builtin_amdgcn_rcpf(1.0f + __expf(2.0f * x));
}

// One workgroup per batch element; persistent over all T steps, both layers
// fused + output head. Thread g in [0,256) owns gate row g of every weight
// matrix, held in VGPRs. States h0/h1 broadcast via LDS; c0 in wave-0 lanes,
// c1 in wave-1 lanes. Wave 2 stages x_{t+1} into LDS (prefetched 2 ahead).
__global__ __launch_bounds__(256, 1)
void lstm2_fused(const float* __restrict__ x,      // [B,T,I]
                 const float* __restrict__ w_ih0,  // [4H,I]
                 const float* __restrict__ w_hh0,  // [4H,H]
                 const float* __restrict__ b_ih0,  // [4H]
                 const float* __restrict__ b_hh0,  // [4H]
                 const float* __restrict__ w_ih1,  // [4H,H]
                 const float* __restrict__ w_hh1,  // [4H,H]
                 const float* __restrict__ b_ih1,  // [4H]
                 const float* __restrict__ b_hh1,  // [4H]
                 const float* __restrict__ w_out,  // [H]
                 const float* __restrict__ b_out,  // [1]
                 float* __restrict__ out)          // [B,T]
{
    const int b = blockIdx.x;
    const int g = threadIdx.x;

    __shared__ float xs[2][II];     // double-buffered x_t
    __shared__ float gates0[GG];
    __shared__ float gates1[GG];
    __shared__ float h0s[HH];
    __shared__ float h1s[HH];

    // ---- weight rows -> registers (uncoalesced but L2-resident: same 320KB
    // for all 256 blocks) ----
    float w0[II], u0[HH], w1[HH], u1[HH];
    {
        const float4* p = (const float4*)(w_ih0 + (size_t)g * II);
        #pragma unroll
        for (int i = 0; i < II/4; ++i) {
            float4 v = p[i];
            w0[4*i] = v.x; w0[4*i+1] = v.y; w0[4*i+2] = v.z; w0[4*i+3] = v.w;
        }
    }
    {
        const float4* p = (const float4*)(w_hh0 + (size_t)g * HH);
        #pragma unroll
        for (int i = 0; i < HH/4; ++i) {
            float4 v = p[i];
            u0[4*i] = v.x; u0[4*i+1] = v.y; u0[4*i+2] = v.z; u0[4*i+3] = v.w;
        }
    }
    {
        const float4* p = (const float4*)(w_ih1 + (size_t)g * HH);
        #pragma unroll
        for (int i = 0; i < HH/4; ++i) {
            float4 v = p[i];
            w1[4*i] = v.x; w1[4*i+1] = v.y; w1[4*i+2] = v.z; w1[4*i+3] = v.w;
        }
    }
    {
        const float4* p = (const float4*)(w_hh1 + (size_t)g * HH);
        #pragma unroll
        for (int i = 0; i < HH/4; ++i) {
            float4 v = p[i];
            u1[4*i] = v.x; u1[4*i+1] = v.y; u1[4*i+2] = v.z; u1[4*i+3] = v.w;
        }
    }
    const float bias0 = b_ih0[g] + b_hh0[g];
    const float bias1 = b_ih1[g] + b_hh1[g];
    const float wout_r = (g >= 64 && g < 128) ? w_out[g - 64] : 0.0f;
    const float bout_r = b_out[0];

    if (g < HH)                h0s[g] = 0.0f;
    if (g >= 64 && g < 128)    h1s[g - 64] = 0.0f;
    float c0 = 0.0f, c1 = 0.0f;

    const float* xb = x + (size_t)b * TT * II;
    float4 xreg = make_float4(0.f, 0.f, 0.f, 0.f);
    if (g >= 128 && g < 160) {              // wave 2, 32 lanes: x stager
        const int q = g - 128;
        ((float4*)&xs[0][0])[q] = ((const float4*)xb)[q];          // x_0
        xreg = ((const float4*)(xb + II))[q];                      // x_1 pending
    }
    __syncthreads();

    float* o_ptr = out + (size_t)b * TT;

    for (int t = 0; t < TT; ++t) {
        // ---------- phase 0: layer-0 gate preactivations (all 256 threads)
        float a0 = bias0, a1 = 0.f, a2 = 0.f, a3 = 0.f;
        const float4* xq = (const float4*)&xs[t & 1][0];
        #pragma unroll
        for (int i = 0; i < II/4; ++i) {           // broadcast LDS reads
            float4 v = xq[i];
            a0 = fmaf(w0[4*i],   v.x, a0);
            a1 = fmaf(w0[4*i+1], v.y, a1);
            a2 = fmaf(w0[4*i+2], v.z, a2);
            a3 = fmaf(w0[4*i+3], v.w, a3);
        }
        const float4* hq = (const float4*)h0s;
        #pragma unroll
        for (int j = 0; j < HH/4; ++j) {
            float4 v = hq[j];
            a0 = fmaf(u0[4*j],   v.x, a0);
            a1 = fmaf(u0[4*j+1], v.y, a1);
            a2 = fmaf(u0[4*j+2], v.z, a2);
            a3 = fmaf(u0[4*j+3], v.w, a3);
        }
        const float pre0 = (a0 + a1) + (a2 + a3);
        gates0[g] = ((g >> 6) == 2) ? fast_tanh(pre0) : fast_sigmoid(pre0);
        __syncthreads();                                        // B1

        // ---------- phase 1: wave 0 = layer-0 c/h update; wave 2 = x staging
        if (g < HH) {
            float ig = gates0[g];
            float fg = gates0[HH + g];
            float gg = gates0[2*HH + g];
            float og = gates0[3*HH + g];
            c0 = fmaf(fg, c0, ig * gg);
            h0s[g] = og * fast_tanh(c0);
        } else if (g >= 128 && g < 160) {
            const int q = g - 128;
            if (t + 1 < TT) ((float4*)&xs[(t + 1) & 1][0])[q] = xreg;
            if (t + 2 < TT) xreg = ((const float4*)(xb + (size_t)(t + 2) * II))[q];
        }
        __syncthreads();                                        // B2

        // ---------- phase 2: layer-1 gate preactivations (all 256 threads)
        float e0 = bias1, e1 = 0.f, e2 = 0.f, e3 = 0.f;
        const float4* h0q = (const float4*)h0s;
        #pragma unroll
        for (int j = 0; j < HH/4; ++j) {
            float4 v = h0q[j];
            e0 = fmaf(w1[4*j],   v.x, e0);
            e1 = fmaf(w1[4*j+1], v.y, e1);
            e2 = fmaf(w1[4*j+2], v.z, e2);
            e3 = fmaf(w1[4*j+3], v.w, e3);
        }
        const float4* h1q = (const float4*)h1s;
        #pragma unroll
        for (int j = 0; j < HH/4; ++j) {
            float4 v = h1q[j];
            e0 = fmaf(u1[4*j],   v.x, e0);
            e1 = fmaf(u1[4*j+1], v.y, e1);
            e2 = fmaf(u1[4*j+2], v.z, e2);
            e3 = fmaf(u1[4*j+3], v.w, e3);
        }
        const float pre1 = (e0 + e1) + (e2 + e3);
        gates1[g] = ((g >> 6) == 2) ? fast_tanh(pre1) : fast_sigmoid(pre1);
        __syncthreads();                                        // B3

        // ---------- phase 3: wave 1 = layer-1 c/h update + output head
        if (g >= 64 && g < 128) {
            const int j = g - 64;
            float ig = gates1[j];
            float fg = gates1[HH + j];
            float gg = gates1[2*HH + j];
            float og = gates1[3*HH + j];
            c1 = fmaf(fg, c1, ig * gg);
            float h1v = og * fast_tanh(c1);
            h1s[j] = h1v;
            float part = h1v * wout_r;
            #pragma unroll
            for (int s = 32; s > 0; s >>= 1) part += __shfl_xor(part, s, 64);
            if (j == 0) o_ptr[t] = fast_sigmoid(part + bout_r);
        }
        __syncthreads();                                        // B4
    }
}

extern "C" void kernel_launch(void* const* d_in, const int* in_sizes, int n_in,
                              void* d_out, int out_size, void* d_ws, size_t ws_size,
                              hipStream_t stream) {
    const float* x     = (const float*)d_in[0];
    const float* w_ih0 = (const float*)d_in[1];
    const float* w_hh0 = (const float*)d_in[2];
    const float* b_ih0 = (const float*)d_in[3];
    const float* b_hh0 = (const float*)d_in[4];
    const float* w_ih1 = (const float*)d_in[5];
    const float* w_hh1 = (const float*)d_in[6];
    const float* b_ih1 = (const float*)d_in[7];
    const float* b_hh1 = (const float*)d_in[8];
    const float* w_out = (const float*)d_in[9];
    const float* b_out = (const float*)d_in[10];
    float* out = (float*)d_out;

    hipLaunchKernelGGL(lstm2_fused, dim3(BB), dim3(256), 0, stream,
                       x, w_ih0, w_hh0, b_ih0, b_hh0,
                       w_ih1, w_hh1, b_ih1, b_hh1, w_out, b_out, out);
}

// Round 2
// 1887.964 us; speedup vs baseline: 1.2472x; 1.2472x over previous
//
#include <hip/hip_runtime.h>

#define BB 256
#define TT 1024
#define II 128
#define HH 64

// fast sigmoid/tanh via v_exp_f32 + v_rcp_f32 (~1e-6 rel err; absmax was 0.0 in R1)
__device__ __forceinline__ float fast_sigmoid(float x) {
    return __builtin_amdgcn_rcpf(1.0f + __expf(-x));
}
__device__ __forceinline__ float fast_tanh(float x) {
    return 1.0f - 2.0f * __builtin_amdgcn_rcpf(1.0f + __expf(2.0f * x));
}

// One workgroup (512 thr = 8 waves) per batch element, persistent over T.
// Each gate row g is SPLIT across two threads (tid=g half=0, tid=256+g half=1)
// so per-thread weight storage is 160 floats -> no VGPR spill (R1 lesson:
// 320 floats/thread forced scratch spills, 180 VGPR + 65% VALU idle).
// Halves combine through LDS partials; single-wave phases do activation +
// c/h update. 4 barriers/step.
__global__ __launch_bounds__(512, 2)
void lstm2_fused(const float* __restrict__ x,      // [B,T,I]
                 const float* __restrict__ w_ih0,  // [4H,I]
                 const float* __restrict__ w_hh0,  // [4H,H]
                 const float* __restrict__ b_ih0,
                 const float* __restrict__ b_hh0,
                 const float* __restrict__ w_ih1,  // [4H,H]
                 const float* __restrict__ w_hh1,  // [4H,H]
                 const float* __restrict__ b_ih1,
                 const float* __restrict__ b_hh1,
                 const float* __restrict__ w_out,  // [H]
                 const float* __restrict__ b_out,  // [1]
                 float* __restrict__ out)          // [B,T]
{
    const int b    = blockIdx.x;
    const int tid  = threadIdx.x;
    const int half = tid >> 8;      // 0 or 1
    const int g    = tid & 255;     // gate row

    __shared__ float xs[2][II];     // double-buffered x_t
    __shared__ float pA[512];       // layer-0 partial dots
    __shared__ float pB[512];       // layer-1 partial dots
    __shared__ float h0s[HH];
    __shared__ float h1s[HH];

    // ---- per-thread weight HALF-rows -> registers (160 floats) ----
    float w0h[II/2], u0h[HH/2], w1h[HH/2], u1h[HH/2];
    {
        const float4* p = (const float4*)(w_ih0 + (size_t)g * II + half * (II/2));
        #pragma unroll
        for (int i = 0; i < II/8; ++i) {
            float4 v = p[i];
            w0h[4*i] = v.x; w0h[4*i+1] = v.y; w0h[4*i+2] = v.z; w0h[4*i+3] = v.w;
        }
    }
    {
        const float4* p = (const float4*)(w_hh0 + (size_t)g * HH + half * (HH/2));
        #pragma unroll
        for (int i = 0; i < HH/8; ++i) {
            float4 v = p[i];
            u0h[4*i] = v.x; u0h[4*i+1] = v.y; u0h[4*i+2] = v.z; u0h[4*i+3] = v.w;
        }
    }
    {
        const float4* p = (const float4*)(w_ih1 + (size_t)g * HH + half * (HH/2));
        #pragma unroll
        for (int i = 0; i < HH/8; ++i) {
            float4 v = p[i];
            w1h[4*i] = v.x; w1h[4*i+1] = v.y; w1h[4*i+2] = v.z; w1h[4*i+3] = v.w;
        }
    }
    {
        const float4* p = (const float4*)(w_hh1 + (size_t)g * HH + half * (HH/2));
        #pragma unroll
        for (int i = 0; i < HH/8; ++i) {
            float4 v = p[i];
            u1h[4*i] = v.x; u1h[4*i+1] = v.y; u1h[4*i+2] = v.z; u1h[4*i+3] = v.w;
        }
    }

    // combine-lane constants (live only in waves 0/1; 4 VGPRs each)
    float bias0[4] = {0,0,0,0}, bias1[4] = {0,0,0,0};
    float wout_r = 0.0f;
    if (tid < 64) {
        #pragma unroll
        for (int k = 0; k < 4; ++k) bias0[k] = b_ih0[64*k + tid] + b_hh0[64*k + tid];
        h0s[tid] = 0.0f;
    } else if (tid < 128) {
        const int j = tid - 64;
        #pragma unroll
        for (int k = 0; k < 4; ++k) bias1[k] = b_ih1[64*k + j] + b_hh1[64*k + j];
        wout_r = w_out[j];
        h1s[j] = 0.0f;
    }
    const float bout_r = b_out[0];
    float c0 = 0.0f, c1 = 0.0f;

    const float* xb = x + (size_t)b * TT * II;
    float4 xreg = make_float4(0.f, 0.f, 0.f, 0.f);
    if (tid >= 256 && tid < 288) {          // wave-4 low half: x stager
        const int q = tid - 256;
        ((float4*)&xs[0][0])[q] = ((const float4*)xb)[q];      // x_0
        xreg = ((const float4*)(xb + II))[q];                  // x_1 pending
    }
    __syncthreads();

    float* o_ptr = out + (size_t)b * TT;

    for (int t = 0; t < TT; ++t) {
        // ---- phase A: layer-0 partial dots (all 512 threads, 96 FMAs each)
        float a0 = 0.f, a1 = 0.f, a2 = 0.f, a3 = 0.f;
        {
            const float4* xq = (const float4*)&xs[t & 1][half * (II/2)];
            #pragma unroll
            for (int i = 0; i < II/8; ++i) {
                float4 v = xq[i];
                a0 = fmaf(w0h[4*i],   v.x, a0);
                a1 = fmaf(w0h[4*i+1], v.y, a1);
                a2 = fmaf(w0h[4*i+2], v.z, a2);
                a3 = fmaf(w0h[4*i+3], v.w, a3);
            }
            const float4* hq = (const float4*)&h0s[half * (HH/2)];
            #pragma unroll
            for (int j = 0; j < HH/8; ++j) {
                float4 v = hq[j];
                a0 = fmaf(u0h[4*j],   v.x, a0);
                a1 = fmaf(u0h[4*j+1], v.y, a1);
                a2 = fmaf(u0h[4*j+2], v.z, a2);
                a3 = fmaf(u0h[4*j+3], v.w, a3);
            }
        }
        pA[tid] = (a0 + a1) + (a2 + a3);
        __syncthreads();                                    // B1

        // ---- combine0: wave 0 -> activations + c0/h0; stagers prefetch x
        if (tid < 64) {
            float pi = pA[tid]       + pA[256 + tid]       + bias0[0];
            float pf = pA[64 + tid]  + pA[320 + tid]       + bias0[1];
            float pg = pA[128 + tid] + pA[384 + tid]       + bias0[2];
            float po = pA[192 + tid] + pA[448 + tid]       + bias0[3];
            float ig = fast_sigmoid(pi);
            float fg = fast_sigmoid(pf);
            float gg = fast_tanh(pg);
            float og = fast_sigmoid(po);
            c0 = fmaf(fg, c0, ig * gg);
            h0s[tid] = og * fast_tanh(c0);
        } else if (tid >= 256 && tid < 288) {
            const int q = tid - 256;
            if (t + 1 < TT) ((float4*)&xs[(t + 1) & 1][0])[q] = xreg;
            if (t + 2 < TT) xreg = ((const float4*)(xb + (size_t)(t + 2) * II))[q];
        }
        __syncthreads();                                    // B2

        // ---- phase B: layer-1 partial dots (all 512 threads, 64 FMAs each)
        float e0 = 0.f, e1 = 0.f, e2 = 0.f, e3 = 0.f;
        {
            const float4* h0q = (const float4*)&h0s[half * (HH/2)];
            #pragma unroll
            for (int j = 0; j < HH/8; ++j) {
                float4 v = h0q[j];
                e0 = fmaf(w1h[4*j],   v.x, e0);
                e1 = fmaf(w1h[4*j+1], v.y, e1);
                e2 = fmaf(w1h[4*j+2], v.z, e2);
                e3 = fmaf(w1h[4*j+3], v.w, e3);
            }
            const float4* h1q = (const float4*)&h1s[half * (HH/2)];
            #pragma unroll
            for (int j = 0; j < HH/8; ++j) {
                float4 v = h1q[j];
                e0 = fmaf(u1h[4*j],   v.x, e0);
                e1 = fmaf(u1h[4*j+1], v.y, e1);
                e2 = fmaf(u1h[4*j+2], v.z, e2);
                e3 = fmaf(u1h[4*j+3], v.w, e3);
            }
        }
        pB[tid] = (e0 + e1) + (e2 + e3);
        __syncthreads();                                    // B3

        // ---- combine1: wave 1 -> activations + c1/h1 + output head
        if (tid >= 64 && tid < 128) {
            const int j = tid - 64;
            float pi = pB[j]        + pB[256 + j]       + bias1[0];
            float pf = pB[64 + j]   + pB[320 + j]       + bias1[1];
            float pg = pB[128 + j]  + pB[384 + j]       + bias1[2];
            float po = pB[192 + j]  + pB[448 + j]       + bias1[3];
            float ig = fast_sigmoid(pi);
            float fg = fast_sigmoid(pf);
            float gg = fast_tanh(pg);
            float og = fast_sigmoid(po);
            c1 = fmaf(fg, c1, ig * gg);
            float h1v = og * fast_tanh(c1);
            h1s[j] = h1v;
            float part = h1v * wout_r;
            #pragma unroll
            for (int s = 32; s > 0; s >>= 1) part += __shfl_xor(part, s, 64);
            if (j == 0) o_ptr[t] = fast_sigmoid(part + bout_r);
        }
        __syncthreads();                                    // B4
    }
}

extern "C" void kernel_launch(void* const* d_in, const int* in_sizes, int n_in,
                              void* d_out, int out_size, void* d_ws, size_t ws_size,
                              hipStream_t stream) {
    const float* x     = (const float*)d_in[0];
    const float* w_ih0 = (const float*)d_in[1];
    const float* w_hh0 = (const float*)d_in[2];
    const float* b_ih0 = (const float*)d_in[3];
    const float* b_hh0 = (const float*)d_in[4];
    const float* w_ih1 = (const float*)d_in[5];
    const float* w_hh1 = (const float*)d_in[6];
    const float* b_ih1 = (const float*)d_in[7];
    const float* b_hh1 = (const float*)d_in[8];
    const float* w_out = (const float*)d_in[9];
    const float* b_out = (const float*)d_in[10];
    float* out = (float*)d_out;

    hipLaunchKernelGGL(lstm2_fused, dim3(BB), dim3(512), 0, stream,
                       x, w_ih0, w_hh0, b_ih0, b_hh0,
                       w_ih1, w_hh1, b_ih1, b_hh1, w_out, b_out, out);
}

// Round 3
// 1526.253 us; speedup vs baseline: 1.5428x; 1.2370x over previous
//
#include <hip/hip_runtime.h>

#define BB 256
#define TT 1024
#define II 128
#define HH 64

// fast sigmoid/tanh via v_exp_f32 + v_rcp_f32 (absmax 0.0 in R1/R2)
__device__ __forceinline__ float fast_sigmoid(float x) {
    return __builtin_amdgcn_rcpf(1.0f + __expf(-x));
}
__device__ __forceinline__ float fast_tanh(float x) {
    return 1.0f - 2.0f * __builtin_amdgcn_rcpf(1.0f + __expf(2.0f * x));
}

// NAMED float4 register declarations — no arrays, no allocas, so SROA must
// promote to VGPRs (R1/R2 lesson: loop-indexed local arrays stayed in
// scratch; VGPR_Count 124 < 160 live floats proved it).
#define DECL4(P, p) float4 P##0=((const float4*)(p))[0], P##1=((const float4*)(p))[1], \
                           P##2=((const float4*)(p))[2], P##3=((const float4*)(p))[3];
#define DECL8(P, p) DECL4(P, p) \
                    float4 P##4=((const float4*)(p))[4], P##5=((const float4*)(p))[5], \
                           P##6=((const float4*)(p))[6], P##7=((const float4*)(p))[7];

// one broadcast float4 operand feeds 8 FMAs (2 rows x 4 cols)
#define FMA4(W, v, x0, x1) x0=fmaf(W.x,v.x,x0); x1=fmaf(W.y,v.y,x1); \
                           x0=fmaf(W.z,v.z,x0); x1=fmaf(W.w,v.w,x1);

// One workgroup (512 thr = 8 waves) per batch element, persistent over T.
// Wave w: column-quarter q=w>>1, row-group rg=w&1. Lane l owns rows
// g0=rg*128+l and g1=g0+64, quarter columns => 160 weight floats in 40 NAMED
// float4 vars. Partials pA/pB[q*256+row] combined by wave 0 (layer 0) /
// wave 1 (layer 1). Wave 2 lanes 0-31 stage x (2 steps ahead).
__global__ __launch_bounds__(512, 2)
void lstm2_fused(const float* __restrict__ x,      // [B,T,I]
                 const float* __restrict__ w_ih0,  // [4H,I]
                 const float* __restrict__ w_hh0,  // [4H,H]
                 const float* __restrict__ b_ih0,
                 const float* __restrict__ b_hh0,
                 const float* __restrict__ w_ih1,  // [4H,H]
                 const float* __restrict__ w_hh1,  // [4H,H]
                 const float* __restrict__ b_ih1,
                 const float* __restrict__ b_hh1,
                 const float* __restrict__ w_out,  // [H]
                 const float* __restrict__ b_out,  // [1]
                 float* __restrict__ out)          // [B,T]
{
    const int bb  = blockIdx.x;
    const int tid = threadIdx.x;
    const int w   = tid >> 6;
    const int l   = tid & 63;
    const int q   = w >> 1;          // column quarter 0..3
    const int rg  = w & 1;           // row group 0..1
    const int g0  = rg * 128 + l;    // first owned row
    const int g1  = g0 + 64;         // second owned row
    const int ps  = q * 256 + g0;    // partial slot for row g0 (g1 = ps+64)

    __shared__ float xs[2][II];
    __shared__ float pA[1024];
    __shared__ float pB[1024];
    __shared__ float h0s[HH];
    __shared__ float h1s[HH];

    // ---- weights: 2 rows x quarter columns, in named registers ----
    DECL8(WA, w_ih0 + g0 * II + q * 32)   // layer0 input, row g0 (32 floats)
    DECL8(WB, w_ih0 + g1 * II + q * 32)   // layer0 input, row g1
    DECL4(UA, w_hh0 + g0 * HH + q * 16)   // layer0 recur, row g0 (16 floats)
    DECL4(UB, w_hh0 + g1 * HH + q * 16)
    DECL4(VA, w_ih1 + g0 * HH + q * 16)   // layer1 input (h0), row g0
    DECL4(VB, w_ih1 + g1 * HH + q * 16)
    DECL4(ZA, w_hh1 + g0 * HH + q * 16)   // layer1 recur, row g0
    DECL4(ZB, w_hh1 + g1 * HH + q * 16)

    // combine-wave constants (wave 0 -> layer0, wave 1 -> layer1)
    float bI = 0.f, bF = 0.f, bG = 0.f, bO = 0.f, cc = 0.f, wout = 0.f;
    if (tid < 64) {
        bI = b_ih0[tid]       + b_hh0[tid];
        bF = b_ih0[64 + tid]  + b_hh0[64 + tid];
        bG = b_ih0[128 + tid] + b_hh0[128 + tid];
        bO = b_ih0[192 + tid] + b_hh0[192 + tid];
        h0s[tid] = 0.0f;
    } else if (tid < 128) {
        const int j = tid - 64;
        bI = b_ih1[j]       + b_hh1[j];
        bF = b_ih1[64 + j]  + b_hh1[64 + j];
        bG = b_ih1[128 + j] + b_hh1[128 + j];
        bO = b_ih1[192 + j] + b_hh1[192 + j];
        wout = w_out[j];
        h1s[j] = 0.0f;
    }
    const float bout = b_out[0];

    const float* xb = x + (size_t)bb * TT * II;
    float4 xreg = make_float4(0.f, 0.f, 0.f, 0.f);
    if (tid >= 128 && tid < 160) {       // wave 2 low half: x stager
        const int sq = tid - 128;
        ((float4*)&xs[0][0])[sq] = ((const float4*)xb)[sq];   // x_0
        xreg = ((const float4*)(xb + II))[sq];                // x_1 pending
    }
    __syncthreads();

    float* o_ptr = out + (size_t)bb * TT;

    for (int t = 0; t < TT; ++t) {
        // ---- phase A: layer-0 partial dots (96 FMAs/thread, 12 bcast b128)
        {
            const float4* xq  = (const float4*)&xs[t & 1][q * 32];
            const float4* h0q = (const float4*)&h0s[q * 16];
            float aa0=0.f, aa1=0.f, ab0=0.f, ab1=0.f;
            { float4 v = xq[0]; FMA4(WA0, v, aa0, aa1) FMA4(WB0, v, ab0, ab1) }
            { float4 v = xq[1]; FMA4(WA1, v, aa0, aa1) FMA4(WB1, v, ab0, ab1) }
            { float4 v = xq[2]; FMA4(WA2, v, aa0, aa1) FMA4(WB2, v, ab0, ab1) }
            { float4 v = xq[3]; FMA4(WA3, v, aa0, aa1) FMA4(WB3, v, ab0, ab1) }
            { float4 v = xq[4]; FMA4(WA4, v, aa0, aa1) FMA4(WB4, v, ab0, ab1) }
            { float4 v = xq[5]; FMA4(WA5, v, aa0, aa1) FMA4(WB5, v, ab0, ab1) }
            { float4 v = xq[6]; FMA4(WA6, v, aa0, aa1) FMA4(WB6, v, ab0, ab1) }
            { float4 v = xq[7]; FMA4(WA7, v, aa0, aa1) FMA4(WB7, v, ab0, ab1) }
            { float4 v = h0q[0]; FMA4(UA0, v, aa0, aa1) FMA4(UB0, v, ab0, ab1) }
            { float4 v = h0q[1]; FMA4(UA1, v, aa0, aa1) FMA4(UB1, v, ab0, ab1) }
            { float4 v = h0q[2]; FMA4(UA2, v, aa0, aa1) FMA4(UB2, v, ab0, ab1) }
            { float4 v = h0q[3]; FMA4(UA3, v, aa0, aa1) FMA4(UB3, v, ab0, ab1) }
            pA[ps]      = aa0 + aa1;
            pA[ps + 64] = ab0 + ab1;
        }
        __syncthreads();                                    // B1

        // ---- combine0 (wave 0) + x staging (wave 2 low half)
        if (tid < 64) {
            float pi = ((pA[tid]       + pA[256 + tid]) + (pA[512 + tid] + pA[768 + tid])) + bI;
            float pf = ((pA[64 + tid]  + pA[320 + tid]) + (pA[576 + tid] + pA[832 + tid])) + bF;
            float pg = ((pA[128 + tid] + pA[384 + tid]) + (pA[640 + tid] + pA[896 + tid])) + bG;
            float po = ((pA[192 + tid] + pA[448 + tid]) + (pA[704 + tid] + pA[960 + tid])) + bO;
            float ig = fast_sigmoid(pi);
            float fg = fast_sigmoid(pf);
            float gg = fast_tanh(pg);
            float og = fast_sigmoid(po);
            cc = fmaf(fg, cc, ig * gg);
            h0s[tid] = og * fast_tanh(cc);
        } else if (tid >= 128 && tid < 160) {
            const int sq = tid - 128;
            if (t + 1 < TT) ((float4*)&xs[(t + 1) & 1][0])[sq] = xreg;
            if (t + 2 < TT) xreg = ((const float4*)(xb + (size_t)(t + 2) * II))[sq];
        }
        __syncthreads();                                    // B2

        // ---- phase B: layer-1 partial dots (64 FMAs/thread, 8 bcast b128)
        {
            const float4* h0q = (const float4*)&h0s[q * 16];   // fresh h0
            const float4* h1q = (const float4*)&h1s[q * 16];
            float ea0=0.f, ea1=0.f, eb0=0.f, eb1=0.f;
            { float4 v = h0q[0]; FMA4(VA0, v, ea0, ea1) FMA4(VB0, v, eb0, eb1) }
            { float4 v = h0q[1]; FMA4(VA1, v, ea0, ea1) FMA4(VB1, v, eb0, eb1) }
            { float4 v = h0q[2]; FMA4(VA2, v, ea0, ea1) FMA4(VB2, v, eb0, eb1) }
            { float4 v = h0q[3]; FMA4(VA3, v, ea0, ea1) FMA4(VB3, v, eb0, eb1) }
            { float4 v = h1q[0]; FMA4(ZA0, v, ea0, ea1) FMA4(ZB0, v, eb0, eb1) }
            { float4 v = h1q[1]; FMA4(ZA1, v, ea0, ea1) FMA4(ZB1, v, eb0, eb1) }
            { float4 v = h1q[2]; FMA4(ZA2, v, ea0, ea1) FMA4(ZB2, v, eb0, eb1) }
            { float4 v = h1q[3]; FMA4(ZA3, v, ea0, ea1) FMA4(ZB3, v, eb0, eb1) }
            pB[ps]      = ea0 + ea1;
            pB[ps + 64] = eb0 + eb1;
        }
        __syncthreads();                                    // B3

        // ---- combine1 (wave 1) + output head
        if (tid >= 64 && tid < 128) {
            const int j = tid - 64;
            float pi = ((pB[j]       + pB[256 + j]) + (pB[512 + j] + pB[768 + j])) + bI;
            float pf = ((pB[64 + j]  + pB[320 + j]) + (pB[576 + j] + pB[832 + j])) + bF;
            float pg = ((pB[128 + j] + pB[384 + j]) + (pB[640 + j] + pB[896 + j])) + bG;
            float po = ((pB[192 + j] + pB[448 + j]) + (pB[704 + j] + pB[960 + j])) + bO;
            float ig = fast_sigmoid(pi);
            float fg = fast_sigmoid(pf);
            float gg = fast_tanh(pg);
            float og = fast_sigmoid(po);
            cc = fmaf(fg, cc, ig * gg);
            float h1v = og * fast_tanh(cc);
            h1s[j] = h1v;
            float part = h1v * wout;
            #pragma unroll
            for (int s = 32; s > 0; s >>= 1) part += __shfl_xor(part, s, 64);
            if (j == 0) o_ptr[t] = fast_sigmoid(part + bout);
        }
        __syncthreads();                                    // B4
    }
}

extern "C" void kernel_launch(void* const* d_in, const int* in_sizes, int n_in,
                              void* d_out, int out_size, void* d_ws, size_t ws_size,
                              hipStream_t stream) {
    const float* x     = (const float*)d_in[0];
    const float* w_ih0 = (const float*)d_in[1];
    const float* w_hh0 = (const float*)d_in[2];
    const float* b_ih0 = (const float*)d_in[3];
    const float* b_hh0 = (const float*)d_in[4];
    const float* w_ih1 = (const float*)d_in[5];
    const float* w_hh1 = (const float*)d_in[6];
    const float* b_ih1 = (const float*)d_in[7];
    const float* b_hh1 = (const float*)d_in[8];
    const float* w_out = (const float*)d_in[9];
    const float* b_out = (const float*)d_in[10];
    float* out = (float*)d_out;

    hipLaunchKernelGGL(lstm2_fused, dim3(BB), dim3(512), 0, stream,
                       x, w_ih0, w_hh0, b_ih0, b_hh0,
                       w_ih1, w_hh1, b_ih1, b_hh1, w_out, b_out, out);
}

// Round 5
// 1499.462 us; speedup vs baseline: 1.5703x; 1.0179x over previous
//
#include <hip/hip_runtime.h>

#define BB 256
#define TT 1024
#define II 128
#define HH 64

__device__ __forceinline__ float fast_sigmoid(float x) {
    return __builtin_amdgcn_rcpf(1.0f + __expf(-x));
}
__device__ __forceinline__ float fast_tanh(float x) {
    return 1.0f - 2.0f * __builtin_amdgcn_rcpf(1.0f + __expf(2.0f * x));
}

// Load a float4 worth of weights into 4 NAMED scalar floats and pin each with
// an opaque asm so the compiler cannot re-materialize (re-load) them inside
// the t-loop. (R3 lesson: named float4s alone still got sunk into the loop —
// VGPR_Count 104 with 160 live floats needed.)
#define DECLW(P, ptr) \
    float4 P##_t = *(const float4*)(ptr); \
    float P##x = P##_t.x, P##y = P##_t.y, P##z = P##_t.z, P##w = P##_t.w; \
    asm volatile("" : "+v"(P##x), "+v"(P##y), "+v"(P##z), "+v"(P##w));

// dual-row FMA: one broadcast float4 v feeds rows A and B (8 FMAs),
// 2 accumulators per row to keep dependency chains short
#define FD(Wa, Wb, v) \
    a0 = fmaf(Wa##x, v.x, a0); a1 = fmaf(Wa##y, v.y, a1); \
    a0 = fmaf(Wa##z, v.z, a0); a1 = fmaf(Wa##w, v.w, a1); \
    b0 = fmaf(Wb##x, v.x, b0); b1 = fmaf(Wb##y, v.y, b1); \
    b0 = fmaf(Wb##z, v.z, b0); b1 = fmaf(Wb##w, v.w, b1);

// One workgroup (512 thr = 8 waves) per batch element, persistent over T.
// Wave w owns hidden indices j in [8w, 8w+8). Lane l = q*16 + gp*8 + jj:
//   rows rA=(2gp)*64+j (gates i/g), rB=rA+64 (gates f/o), column quarter q.
// Full preact = shfl_xor(16)+shfl_xor(32) over quarters (bias added AFTER the
// reduction — R4 bug was 4x bias); gate gather = shfl_xor(8); c/h updated
// redundantly in all 8 lanes of j. 2 barriers/step. h0s/h1s double-buffered;
// x 4-deep, prefetched 2 ahead by wave 0.
__global__ __launch_bounds__(512, 2)
void lstm2_fused(const float* __restrict__ x,      // [B,T,I]
                 const float* __restrict__ w_ih0,  // [4H,I]
                 const float* __restrict__ w_hh0,  // [4H,H]
                 const float* __restrict__ b_ih0,
                 const float* __restrict__ b_hh0,
                 const float* __restrict__ w_ih1,  // [4H,H]
                 const float* __restrict__ w_hh1,  // [4H,H]
                 const float* __restrict__ b_ih1,
                 const float* __restrict__ b_hh1,
                 const float* __restrict__ w_out,  // [H]
                 const float* __restrict__ b_out,  // [1]
                 float* __restrict__ outp)         // [B,T]
{
    const int bb  = blockIdx.x;
    const int tid = threadIdx.x;
    const int w   = tid >> 6;
    const int l   = tid & 63;
    const int q   = l >> 4;          // column quarter
    const int gp  = (l >> 3) & 1;    // gate pair: 0 -> {i,f}, 1 -> {g,o}
    const int jj  = l & 7;
    const int j   = 8 * w + jj;      // hidden index owned
    const int rA  = (2 * gp) * 64 + j;
    const int rB  = rA + 64;

    // padded quarters: x stride 36 dwords, h stride 20 dwords (conflict-free)
    __shared__ __align__(16) float xs[4][144];
    __shared__ __align__(16) float h0s[2][80];
    __shared__ __align__(16) float h1s[2][80];

    // ---- weights -> pinned VGPRs (160 floats/lane) ----
    const float* pWA = w_ih0 + rA * II + q * 32;
    const float* pWB = w_ih0 + rB * II + q * 32;
    DECLW(WA0, pWA +  0) DECLW(WA1, pWA +  4) DECLW(WA2, pWA +  8) DECLW(WA3, pWA + 12)
    DECLW(WA4, pWA + 16) DECLW(WA5, pWA + 20) DECLW(WA6, pWA + 24) DECLW(WA7, pWA + 28)
    DECLW(WB0, pWB +  0) DECLW(WB1, pWB +  4) DECLW(WB2, pWB +  8) DECLW(WB3, pWB + 12)
    DECLW(WB4, pWB + 16) DECLW(WB5, pWB + 20) DECLW(WB6, pWB + 24) DECLW(WB7, pWB + 28)
    const float* pUA = w_hh0 + rA * HH + q * 16;
    const float* pUB = w_hh0 + rB * HH + q * 16;
    DECLW(UA0, pUA + 0) DECLW(UA1, pUA + 4) DECLW(UA2, pUA + 8) DECLW(UA3, pUA + 12)
    DECLW(UB0, pUB + 0) DECLW(UB1, pUB + 4) DECLW(UB2, pUB + 8) DECLW(UB3, pUB + 12)
    const float* pVA = w_ih1 + rA * HH + q * 16;
    const float* pVB = w_ih1 + rB * HH + q * 16;
    DECLW(VA0, pVA + 0) DECLW(VA1, pVA + 4) DECLW(VA2, pVA + 8) DECLW(VA3, pVA + 12)
    DECLW(VB0, pVB + 0) DECLW(VB1, pVB + 4) DECLW(VB2, pVB + 8) DECLW(VB3, pVB + 12)
    const float* pZA = w_hh1 + rA * HH + q * 16;
    const float* pZB = w_hh1 + rB * HH + q * 16;
    DECLW(ZA0, pZA + 0) DECLW(ZA1, pZA + 4) DECLW(ZA2, pZA + 8) DECLW(ZA3, pZA + 12)
    DECLW(ZB0, pZB + 0) DECLW(ZB1, pZB + 4) DECLW(ZB2, pZB + 8) DECLW(ZB3, pZB + 12)

    float bA0 = b_ih0[rA] + b_hh0[rA];
    float bB0 = b_ih0[rB] + b_hh0[rB];
    float bA1 = b_ih1[rA] + b_hh1[rA];
    float bB1 = b_ih1[rB] + b_hh1[rB];
    float wout = w_out[l];
    float bout = b_out[0];
    asm volatile("" : "+v"(bA0), "+v"(bB0), "+v"(bA1), "+v"(bB1), "+v"(wout), "+v"(bout));

    float c0 = 0.0f, c1 = 0.0f;
    const float* xb = x + (size_t)bb * TT * II;
    float* op = outp + (size_t)bb * TT;

    // zero the t=0 "previous" state buffers
    if (tid < 80)       h0s[1][tid] = 0.0f;
    else if (tid < 160) h1s[1][tid - 80] = 0.0f;

    // x stager mapping: lane l holds x cols {2l, 2l+1}
    const int sidx = (l >> 4) * 36 + 2 * (l & 15);
    if (w == 0) {
        float2 r0 = ((const float2*)xb)[l];
        float2 r1 = ((const float2*)(xb + II))[l];
        *(float2*)&xs[0][sidx] = r0;
        *(float2*)&xs[1][sidx] = r1;
    }
    __syncthreads();

    float2 xr = make_float2(0.f, 0.f);

    for (int t = 0; t < TT; ++t) {
        const int cur = t & 1, prv = cur ^ 1;

        // wave 0: issue global prefetch of x(t+2) (lands well before use)
        if (w == 0 && t + 2 < TT)
            xr = ((const float2*)(xb + (size_t)(t + 2) * II))[l];

        // wave 7: output head for step t-1 (reads h1 of prev step)
        if (w == 7 && t > 0) {
            float hv = h1s[prv][(l >> 4) * 20 + (l & 15)];
            float part = hv * wout;
            #pragma unroll
            for (int sh = 32; sh > 0; sh >>= 1) part += __shfl_xor(part, sh, 64);
            if (l == 0) op[t - 1] = fast_sigmoid(part + bout);
        }

        // ---- phase A: layer-0 dots (96 FMAs/lane, rows rA,rB, quarter q)
        float a0 = 0.f, a1 = 0.f, b0 = 0.f, b1 = 0.f;
        {
            const float4* xq = (const float4*)&xs[t & 3][q * 36];
            float4 v;
            v = xq[0]; FD(WA0, WB0, v)  v = xq[1]; FD(WA1, WB1, v)
            v = xq[2]; FD(WA2, WB2, v)  v = xq[3]; FD(WA3, WB3, v)
            v = xq[4]; FD(WA4, WB4, v)  v = xq[5]; FD(WA5, WB5, v)
            v = xq[6]; FD(WA6, WB6, v)  v = xq[7]; FD(WA7, WB7, v)
            const float4* hq = (const float4*)&h0s[prv][q * 20];
            v = hq[0]; FD(UA0, UB0, v)  v = hq[1]; FD(UA1, UB1, v)
            v = hq[2]; FD(UA2, UB2, v)  v = hq[3]; FD(UA3, UB3, v)
        }
        {
            float pA = a0 + a1;
            float pB = b0 + b1;
            pA += __shfl_xor(pA, 16, 64); pA += __shfl_xor(pA, 32, 64);
            pB += __shfl_xor(pB, 16, 64); pB += __shfl_xor(pB, 32, 64);
            pA += bA0;                       // bias AFTER reduction (R4 fix)
            pB += bB0;
            float sA = fast_sigmoid(pA), tA = fast_tanh(pA);
            float actA = gp ? tA : sA;          // rA: i (sig) or g (tanh)
            float actB = fast_sigmoid(pB);      // rB: f or o (both sig)
            float oA = __shfl_xor(actA, 8, 64);
            float oB = __shfl_xor(actB, 8, 64);
            float ig = gp ? oA : actA;
            float fg = gp ? oB : actB;
            float gg = gp ? actA : oA;
            float og = gp ? actB : oB;
            c0 = fmaf(fg, c0, ig * gg);
            float h0v = og * fast_tanh(c0);
            if (l < 8) h0s[cur][(w >> 1) * 20 + ((w & 1) << 3) + l] = h0v;
        }
        __syncthreads();                                    // B1

        // ---- phase B: layer-1 dots (64 FMAs/lane)
        a0 = 0.f; a1 = 0.f; b0 = 0.f; b1 = 0.f;
        {
            const float4* g0q = (const float4*)&h0s[cur][q * 20];  // fresh h0(t)
            const float4* g1q = (const float4*)&h1s[prv][q * 20];  // h1(t-1)
            float4 v;
            v = g0q[0]; FD(VA0, VB0, v)  v = g0q[1]; FD(VA1, VB1, v)
            v = g0q[2]; FD(VA2, VB2, v)  v = g0q[3]; FD(VA3, VB3, v)
            v = g1q[0]; FD(ZA0, ZB0, v)  v = g1q[1]; FD(ZA1, ZB1, v)
            v = g1q[2]; FD(ZA2, ZB2, v)  v = g1q[3]; FD(ZA3, ZB3, v)
        }
        {
            float pA = a0 + a1;
            float pB = b0 + b1;
            pA += __shfl_xor(pA, 16, 64); pA += __shfl_xor(pA, 32, 64);
            pB += __shfl_xor(pB, 16, 64); pB += __shfl_xor(pB, 32, 64);
            pA += bA1;                       // bias AFTER reduction (R4 fix)
            pB += bB1;
            float sA = fast_sigmoid(pA), tA = fast_tanh(pA);
            float actA = gp ? tA : sA;
            float actB = fast_sigmoid(pB);
            float oA = __shfl_xor(actA, 8, 64);
            float oB = __shfl_xor(actB, 8, 64);
            float ig = gp ? oA : actA;
            float fg = gp ? oB : actB;
            float gg = gp ? actA : oA;
            float og = gp ? actB : oB;
            c1 = fmaf(fg, c1, ig * gg);
            float h1v = og * fast_tanh(c1);
            if (l < 8) h1s[cur][(w >> 1) * 20 + ((w & 1) << 3) + l] = h1v;
        }
        // wave 0: commit x(t+2) prefetch to LDS (consumed at phase A of t+2)
        if (w == 0 && t + 2 < TT) *(float2*)&xs[(t + 2) & 3][sidx] = xr;
        __syncthreads();                                    // B2
    }

    // tail: output for t = TT-1
    if (w == 7) {
        float hv = h1s[(TT - 1) & 1][(l >> 4) * 20 + (l & 15)];
        float part = hv * wout;
        #pragma unroll
        for (int sh = 32; sh > 0; sh >>= 1) part += __shfl_xor(part, sh, 64);
        if (l == 0) op[TT - 1] = fast_sigmoid(part + bout);
    }
}

extern "C" void kernel_launch(void* const* d_in, const int* in_sizes, int n_in,
                              void* d_out, int out_size, void* d_ws, size_t ws_size,
                              hipStream_t stream) {
    const float* x     = (const float*)d_in[0];
    const float* w_ih0 = (const float*)d_in[1];
    const float* w_hh0 = (const float*)d_in[2];
    const float* b_ih0 = (const float*)d_in[3];
    const float* b_hh0 = (const float*)d_in[4];
    const float* w_ih1 = (const float*)d_in[5];
    const float* w_hh1 = (const float*)d_in[6];
    const float* b_ih1 = (const float*)d_in[7];
    const float* b_hh1 = (const float*)d_in[8];
    const float* w_out = (const float*)d_in[9];
    const float* b_out = (const float*)d_in[10];
    float* out = (float*)d_out;

    hipLaunchKernelGGL(lstm2_fused, dim3(BB), dim3(512), 0, stream,
                       x, w_ih0, w_hh0, b_ih0, b_hh0,
                       w_ih1, w_hh1, b_ih1, b_hh1, w_out, b_out, out);
}

// Round 6
// 1143.496 us; speedup vs baseline: 2.0592x; 1.3113x over previous
//
#include <hip/hip_runtime.h>

#define BB 256
#define TT 1024
#define II 128
#define HH 64

typedef _Float16 h2 __attribute__((ext_vector_type(2)));
typedef unsigned int uint;

#if __has_builtin(__builtin_amdgcn_fdot2)
#define DOT2(a, b, c) __builtin_amdgcn_fdot2((a), (b), (c), false)
#else
#define DOT2(a, b, c) fmaf((float)(a)[0], (float)(b)[0], fmaf((float)(a)[1], (float)(b)[1], (c)))
#endif

#define BC(u) __builtin_bit_cast(h2, (uint)(u))

// load 2 f32 -> packed f16 (RNE) in a NAMED uint reg
#define LDPK(P, ptr) uint P; { float2 _f = *(const float2*)(ptr); \
    h2 _h; _h[0] = (_Float16)_f.x; _h[1] = (_Float16)_f.y; \
    P = __builtin_bit_cast(uint, _h); }

#define PIN8(a,b,c,d,e,f,g,h_) asm volatile("" : "+v"(a),"+v"(b),"+v"(c),"+v"(d),"+v"(e),"+v"(f),"+v"(g),"+v"(h_));

// 8 packs (16 floats) from base+o, pinned so they can't be re-materialized
#define LD8(P, base, o) \
    LDPK(P##0,(base)+(o)+ 0) LDPK(P##1,(base)+(o)+ 2) LDPK(P##2,(base)+(o)+ 4) LDPK(P##3,(base)+(o)+ 6) \
    LDPK(P##4,(base)+(o)+ 8) LDPK(P##5,(base)+(o)+10) LDPK(P##6,(base)+(o)+12) LDPK(P##7,(base)+(o)+14) \
    PIN8(P##0,P##1,P##2,P##3,P##4,P##5,P##6,P##7)

// 8 weight packs vs 2 broadcast uint4 (16 input vals), 4 accumulator chains
#define D8(P, va, vb) \
    a0 = DOT2(BC(P##0), BC((va).x), a0); a1 = DOT2(BC(P##1), BC((va).y), a1); \
    a2 = DOT2(BC(P##2), BC((va).z), a2); a3 = DOT2(BC(P##3), BC((va).w), a3); \
    a0 = DOT2(BC(P##4), BC((vb).x), a0); a1 = DOT2(BC(P##5), BC((vb).y), a1); \
    a2 = DOT2(BC(P##6), BC((vb).z), a2); a3 = DOT2(BC(P##7), BC((vb).w), a3);

// One workgroup (512 thr = 8 waves) per batch element, persistent over T.
// WAVE-SPECIALIZED PIPELINE: waves 0-3 = layer 0 (compute h0(k)); waves 4-7 =
// layer 1 (compute h1(k-1) from h0(k-1)) — independent chains, concurrent,
// ONE barrier per iteration. Each lane owns one full gate row in packed-f16
// VGPRs (f32 accumulate via v_dot2_f32_f16): L0 = 96 packs, L1 = 64. Gate
// gather = 3 shfl_xor; no reduction shuffles. Wave 4 also runs the output
// head (for step k-2); wave 7 stages x (2 steps ahead, f16).
// amdgpu_waves_per_eu(2,2): clamp occupancy so the allocator keeps pinned
// weights in arch VGPRs (R5: targeting >2 waves/EU pushed them to AGPRs).
__global__ __launch_bounds__(512) __attribute__((amdgpu_waves_per_eu(2, 2)))
void lstm2_fused(const float* __restrict__ x,      // [B,T,I]
                 const float* __restrict__ w_ih0,  // [4H,I]
                 const float* __restrict__ w_hh0,  // [4H,H]
                 const float* __restrict__ b_ih0,
                 const float* __restrict__ b_hh0,
                 const float* __restrict__ w_ih1,  // [4H,H]
                 const float* __restrict__ w_hh1,  // [4H,H]
                 const float* __restrict__ b_ih1,
                 const float* __restrict__ b_hh1,
                 const float* __restrict__ w_out,  // [H]
                 const float* __restrict__ b_out,  // [1]
                 float* __restrict__ outp)         // [B,T]
{
    const int bb  = blockIdx.x;
    const int tid = threadIdx.x;
    const int w   = tid >> 6;
    const int l   = tid & 63;
    const int g   = l >> 4;             // gate 0..3 (i,f,g,o)
    const int j   = 16 * (w & 3) + (l & 15);   // hidden index 0..63
    const int r   = g * 64 + j;         // gate-matrix row
    const bool isL0 = (w < 4);

    __shared__ __align__(16) uint xsh[4][64];    // x(t) as 64 f16x2 packs
    __shared__ __align__(16) uint h0sh[2][32];   // h0 as 32 packs
    __shared__ __align__(16) uint h1sh[2][32];

    // unified weight-pointer scheme (wave-uniform selects):
    // L0: G0-7 = w_ih0 row (128f), G8-11 = w_hh0 row (64f)
    // L1: G0-3 = w_ih1 row (64f), G4-7 = w_hh1 row (64f), G8-11 unused dup
    const float* qA = isL0 ? (w_ih0 + (size_t)r * II)      : (w_ih1 + (size_t)r * HH);
    const float* qB = isL0 ? (w_ih0 + (size_t)r * II + 64) : (w_hh1 + (size_t)r * HH);
    const float* qC = isL0 ? (w_hh0 + (size_t)r * HH)      : (w_ih1 + (size_t)r * HH);

    LD8(G0, qA,  0) LD8(G1, qA, 16) LD8(G2, qA, 32) LD8(G3, qA, 48)
    LD8(G4, qB,  0) LD8(G5, qB, 16) LD8(G6, qB, 32) LD8(G7, qB, 48)
    LD8(G8, qC,  0) LD8(G9, qC, 16) LD8(G10, qC, 32) LD8(G11, qC, 48)

    float bias = isL0 ? (b_ih0[r] + b_hh0[r]) : (b_ih1[r] + b_hh1[r]);
    float2 wo  = ((const float2*)w_out)[l & 31];
    float bout = b_out[0];
    // unified activation: act = (a*y + b) * rcp(y+1), y = exp(n*pre)
    // gates i,f,o: n=-1,a=0,b=1 (sigmoid); gate g: n=2,a=1,b=-1 (tanh)
    const float nsc = (g == 2) ?  2.0f : -1.0f;
    const float aco = (g == 2) ?  1.0f :  0.0f;
    const float bco = (g == 2) ? -1.0f :  1.0f;

    float cst = 0.0f;                   // persistent c (per owned j, redundant x4)
    const float* xb = x + (size_t)bb * TT * II;
    float* op = outp + (size_t)bb * TT;

    // prologue: zero h0(-1), h1(-1); stage x(0), x(1)
    if (tid < 32)      h0sh[1][tid] = 0u;
    else if (tid < 64) h1sh[1][tid - 32] = 0u;
    if (w == 7) {
        float2 f0 = ((const float2*)xb)[l];
        float2 f1 = ((const float2*)(xb + II))[l];
        h2 p0; p0[0] = (_Float16)f0.x; p0[1] = (_Float16)f0.y;
        h2 p1; p1[0] = (_Float16)f1.x; p1[1] = (_Float16)f1.y;
        xsh[0][l] = __builtin_bit_cast(uint, p0);
        xsh[1][l] = __builtin_bit_cast(uint, p1);
    }
    __syncthreads();

    float2 xr = make_float2(0.f, 0.f);

    for (int k = 0; k < TT + 2; ++k) {
        // wave 7: issue x(k+2) global prefetch (lands during dot phase)
        if (w == 7 && k + 2 < TT)
            xr = ((const float2*)(xb + (size_t)(k + 2) * II))[l];

        // wave 4: output head for step k-2 (h1(k-2) in slot k&1)
        if (w == 4 && k >= 2) {
            h2 hp = BC(h1sh[k & 1][l & 31]);
            float part = (l < 32) ? fmaf((float)hp[0], wo.x, (float)hp[1] * wo.y) : 0.0f;
            #pragma unroll
            for (int sh = 1; sh < 64; sh <<= 1) part += __shfl_xor(part, sh, 64);
            if (l == 0) op[k - 2] = __builtin_amdgcn_rcpf(1.0f + __expf(-(part + bout)));
        }

        const bool active = isL0 ? (k < TT) : (k >= 1 && k <= TT);
        if (active) {
            float a0 = 0.f, a1 = 0.f, a2 = 0.f, a3 = 0.f;
            if (isL0) {
                // h0(k) = lstm0(x(k), h0(k-1))
                const uint4* xq = (const uint4*)&xsh[k & 3][0];
                uint4 v0, v1;
                v0 = xq[ 0]; v1 = xq[ 1]; D8(G0, v0, v1)
                v0 = xq[ 2]; v1 = xq[ 3]; D8(G1, v0, v1)
                v0 = xq[ 4]; v1 = xq[ 5]; D8(G2, v0, v1)
                v0 = xq[ 6]; v1 = xq[ 7]; D8(G3, v0, v1)
                v0 = xq[ 8]; v1 = xq[ 9]; D8(G4, v0, v1)
                v0 = xq[10]; v1 = xq[11]; D8(G5, v0, v1)
                v0 = xq[12]; v1 = xq[13]; D8(G6, v0, v1)
                v0 = xq[14]; v1 = xq[15]; D8(G7, v0, v1)
                const uint4* hq = (const uint4*)&h0sh[(k + 1) & 1][0];
                v0 = hq[0]; v1 = hq[1]; D8(G8,  v0, v1)
                v0 = hq[2]; v1 = hq[3]; D8(G9,  v0, v1)
                v0 = hq[4]; v1 = hq[5]; D8(G10, v0, v1)
                v0 = hq[6]; v1 = hq[7]; D8(G11, v0, v1)
            } else {
                // h1(k-1) = lstm1(h0(k-1), h1(k-2))
                const uint4* aq = (const uint4*)&h0sh[(k + 1) & 1][0];
                const uint4* bq = (const uint4*)&h1sh[k & 1][0];
                uint4 v0, v1;
                v0 = aq[0]; v1 = aq[1]; D8(G0, v0, v1)
                v0 = aq[2]; v1 = aq[3]; D8(G1, v0, v1)
                v0 = aq[4]; v1 = aq[5]; D8(G2, v0, v1)
                v0 = aq[6]; v1 = aq[7]; D8(G3, v0, v1)
                v0 = bq[0]; v1 = bq[1]; D8(G4, v0, v1)
                v0 = bq[2]; v1 = bq[3]; D8(G5, v0, v1)
                v0 = bq[4]; v1 = bq[5]; D8(G6, v0, v1)
                v0 = bq[6]; v1 = bq[7]; D8(G7, v0, v1)
            }
            float pre = ((a0 + a1) + (a2 + a3)) + bias;
            float y   = __expf(nsc * pre);
            float rr  = __builtin_amdgcn_rcpf(y + 1.0f);
            float act = fmaf(aco, y, bco) * rr;
            // gather 4 gates of own j: lanes l^16, l^32, l^48 hold gates g^1,g^2,g^3
            float s0 = act;
            float s1 = __shfl_xor(s0, 16, 64);
            float s2 = __shfl_xor(s0, 32, 64);
            float s3 = __shfl_xor(s1, 32, 64);
            const bool gb0 = (g & 1) != 0, gb1 = (g & 2) != 0;
            float pig = gb0 ? s1 * s3 : s0 * s2;                 // i * g
            float ff  = gb0 ? (gb1 ? s2 : s0) : (gb1 ? s3 : s1); // f
            float oo  = gb0 ? (gb1 ? s0 : s2) : (gb1 ? s1 : s3); // o
            cst = fmaf(ff, cst, pig);
            float y2 = __expf(2.0f * cst);
            float th = (y2 - 1.0f) * __builtin_amdgcn_rcpf(y2 + 1.0f);
            float hval = oo * th;
            if (g == 0) {   // one lane per j writes the f16 h value
                if (isL0) ((_Float16*)&h0sh[k & 1][0])[j]       = (_Float16)hval;
                else      ((_Float16*)&h1sh[(k - 1) & 1][0])[j] = (_Float16)hval;
            }
        }

        // wave 7: commit x(k+2) to LDS (consumed at iteration k+2)
        if (w == 7 && k + 2 < TT) {
            h2 p; p[0] = (_Float16)xr.x; p[1] = (_Float16)xr.y;
            xsh[(k + 2) & 3][l] = __builtin_bit_cast(uint, p);
        }
        __syncthreads();
    }
}

extern "C" void kernel_launch(void* const* d_in, const int* in_sizes, int n_in,
                              void* d_out, int out_size, void* d_ws, size_t ws_size,
                              hipStream_t stream) {
    const float* x     = (const float*)d_in[0];
    const float* w_ih0 = (const float*)d_in[1];
    const float* w_hh0 = (const float*)d_in[2];
    const float* b_ih0 = (const float*)d_in[3];
    const float* b_hh0 = (const float*)d_in[4];
    const float* w_ih1 = (const float*)d_in[5];
    const float* w_hh1 = (const float*)d_in[6];
    const float* b_ih1 = (const float*)d_in[7];
    const float* b_hh1 = (const float*)d_in[8];
    const float* w_out = (const float*)d_in[9];
    const float* b_out = (const float*)d_in[10];
    float* out = (float*)d_out;

    hipLaunchKernelGGL(lstm2_fused, dim3(BB), dim3(512), 0, stream,
                       x, w_ih0, w_hh0, b_ih0, b_hh0,
                       w_ih1, w_hh1, b_ih1, b_hh1, w_out, b_out, out);
}

// Round 7
// 1037.568 us; speedup vs baseline: 2.2694x; 1.1021x over previous
//
#include <hip/hip_runtime.h>

#define BB 256
#define TT 1024
#define II 128
#define HH 64
#define BT (BB * TT)

typedef _Float16 h2 __attribute__((ext_vector_type(2)));
typedef _Float16 half8 __attribute__((ext_vector_type(8)));
typedef float f32x4 __attribute__((ext_vector_type(4)));
typedef unsigned int uint;
typedef unsigned short ushort;

#define DOT2(a, b, c) __builtin_amdgcn_fdot2((a), (b), (c), false)
#define BC(u) __builtin_bit_cast(h2, (uint)(u))

#define LDPK(P, ptr) uint P; { float2 _f = *(const float2*)(ptr); \
    h2 _h; _h[0] = (_Float16)_f.x; _h[1] = (_Float16)_f.y; \
    P = __builtin_bit_cast(uint, _h); }
#define PIN8(a,b,c,d,e,f,g,h_) asm volatile("" : "+v"(a),"+v"(b),"+v"(c),"+v"(d),"+v"(e),"+v"(f),"+v"(g),"+v"(h_));
#define LD8(P, base, o) \
    LDPK(P##0,(base)+(o)+ 0) LDPK(P##1,(base)+(o)+ 2) LDPK(P##2,(base)+(o)+ 4) LDPK(P##3,(base)+(o)+ 6) \
    LDPK(P##4,(base)+(o)+ 8) LDPK(P##5,(base)+(o)+10) LDPK(P##6,(base)+(o)+12) LDPK(P##7,(base)+(o)+14) \
    PIN8(P##0,P##1,P##2,P##3,P##4,P##5,P##6,P##7)

#define D8(P, va, vb) \
    a0 = DOT2(BC(P##0), BC((va).x), a0); a1 = DOT2(BC(P##1), BC((va).y), a1); \
    a2 = DOT2(BC(P##2), BC((va).z), a2); a3 = DOT2(BC(P##3), BC((va).w), a3); \
    a0 = DOT2(BC(P##4), BC((vb).x), a0); a1 = DOT2(BC(P##5), BC((vb).y), a1); \
    a2 = DOT2(BC(P##6), BC((vb).z), a2); a3 = DOT2(BC(P##7), BC((vb).w), a3);

// ============ Kernel A: xg[bt, r] = sum_i x[bt,i] * w_ih0[r,i]  (f16 out) ====
// MFMA 16x16x32 f16. A-frag: A[m][k], m=lane&15, k=(lane>>4)*8+j.
// B-frag: B[k][n], n=lane&15, k=(lane>>4)*8+j  (B[k][n] = w_ih0[n][k]).
// C/D:    col=lane&15, row=(lane>>4)*4+reg.   (guide §3, m89/m91-verified)
__global__ __launch_bounds__(256)
void xg_mfma(const float* __restrict__ x, const float* __restrict__ w_ih0,
             ushort* __restrict__ xg)
{
    __shared__ __align__(16) _Float16 xt[64][136];    // 64 rows x 128 K (+8 pad)
    __shared__ __align__(16) _Float16 wt[128][136];   // 128 n x 128 K (+8 pad)

    const int tid  = threadIdx.x;
    const int lane = tid & 63;
    const int wv   = tid >> 6;
    const int bt0  = blockIdx.x * 64;

    // stage x tile (f32 -> f16)
    {
        const int row = tid >> 2, q = (tid & 3) * 32;
        const float4* src = (const float4*)(x + (size_t)(bt0 + row) * II + q);
        _Float16* dst = &xt[row][q];
        #pragma unroll
        for (int i = 0; i < 8; ++i) {
            float4 v = src[i];
            dst[4*i+0] = (_Float16)v.x; dst[4*i+1] = (_Float16)v.y;
            dst[4*i+2] = (_Float16)v.z; dst[4*i+3] = (_Float16)v.w;
        }
    }

    for (int nh = 0; nh < 2; ++nh) {
        __syncthreads();    // nh=0: x staged; nh=1: protect wt from readers
        {   // stage w half: 128 n-rows x 128 K
            const int n = tid >> 1, kh = (tid & 1) * 64;
            const float4* src = (const float4*)(w_ih0 + (size_t)(nh * 128 + n) * II + kh);
            _Float16* dst = &wt[n][kh];
            #pragma unroll
            for (int i = 0; i < 16; ++i) {
                float4 v = src[i];
                dst[4*i+0] = (_Float16)v.x; dst[4*i+1] = (_Float16)v.y;
                dst[4*i+2] = (_Float16)v.z; dst[4*i+3] = (_Float16)v.w;
            }
        }
        __syncthreads();

        const int m  = wv * 16 + (lane & 15);
        const int kf = (lane >> 4) * 8;
        half8 a0 = *(const half8*)&xt[m][ 0 + kf];
        half8 a1 = *(const half8*)&xt[m][32 + kf];
        half8 a2 = *(const half8*)&xt[m][64 + kf];
        half8 a3 = *(const half8*)&xt[m][96 + kf];

        #pragma unroll
        for (int nt = 0; nt < 8; ++nt) {
            const int nloc = nt * 16 + (lane & 15);
            half8 b0 = *(const half8*)&wt[nloc][ 0 + kf];
            half8 b1 = *(const half8*)&wt[nloc][32 + kf];
            half8 b2 = *(const half8*)&wt[nloc][64 + kf];
            half8 b3 = *(const half8*)&wt[nloc][96 + kf];
            f32x4 acc = {0.f, 0.f, 0.f, 0.f};
            acc = __builtin_amdgcn_mfma_f32_16x16x32_f16(a0, b0, acc, 0, 0, 0);
            acc = __builtin_amdgcn_mfma_f32_16x16x32_f16(a1, b1, acc, 0, 0, 0);
            acc = __builtin_amdgcn_mfma_f32_16x16x32_f16(a2, b2, acc, 0, 0, 0);
            acc = __builtin_amdgcn_mfma_f32_16x16x32_f16(a3, b3, acc, 0, 0, 0);
            const int col = nh * 128 + nt * 16 + (lane & 15);
            const int r0  = wv * 16 + (lane >> 4) * 4;
            #pragma unroll
            for (int r = 0; r < 4; ++r) {
                _Float16 hv = (_Float16)acc[r];
                xg[(size_t)(bt0 + r0 + r) * 256 + col] = __builtin_bit_cast(ushort, hv);
            }
        }
    }
}

// ============ Kernel B: persistent 2-layer recurrence ========================
// 256 blocks x 512 thr. Waves 0-3: L0 (h-recurrence only: 32 packs w_hh0).
// Waves 4-7: L1 (64 packs w_ih1+w_hh1). x contribution read from xg (f16
// scalar, prefetched 1 step ahead). h1 streamed to h1g. 1 barrier/step.
__global__ __launch_bounds__(512) __attribute__((amdgpu_waves_per_eu(2, 2)))
void lstm2_core(const float* __restrict__ w_hh0,
                const float* __restrict__ b_ih0, const float* __restrict__ b_hh0,
                const float* __restrict__ w_ih1, const float* __restrict__ w_hh1,
                const float* __restrict__ b_ih1, const float* __restrict__ b_hh1,
                const ushort* __restrict__ xg, ushort* __restrict__ h1g)
{
    const int bb  = blockIdx.x;
    const int tid = threadIdx.x;
    const int w   = tid >> 6;
    const int l   = tid & 63;
    const int g   = l >> 4;                    // gate 0..3 (i,f,g,o)
    const int j   = 16 * (w & 3) + (l & 15);   // hidden index
    const int r   = g * 64 + j;                // gate-matrix row
    const bool isL0 = (w < 4);

    __shared__ __align__(16) uint h0sh[2][32];
    __shared__ __align__(16) uint h1sh[2][32];

    const float* qA = isL0 ? (w_hh0 + (size_t)r * HH) : (w_ih1 + (size_t)r * HH);
    const float* qB = isL0 ? (w_hh0 + (size_t)r * HH) : (w_hh1 + (size_t)r * HH);
    LD8(G0, qA,  0) LD8(G1, qA, 16) LD8(G2, qA, 32) LD8(G3, qA, 48)
    LD8(G4, qB,  0) LD8(G5, qB, 16) LD8(G6, qB, 32) LD8(G7, qB, 48)

    float bias = isL0 ? (b_ih0[r] + b_hh0[r]) : (b_ih1[r] + b_hh1[r]);
    // unified activation: act = (a*y + b) * rcp(y+1), y = exp(n*pre)
    const float nsc = (g == 2) ?  2.0f : -1.0f;
    const float aco = (g == 2) ?  1.0f :  0.0f;
    const float bco = (g == 2) ? -1.0f :  1.0f;

    float cst = 0.0f;
    const ushort* xgb = xg + (size_t)bb * TT * 256 + r;   // L0 lanes only
    ushort* h1b = h1g + (size_t)bb * TT * 64;

    if (tid < 32)      h0sh[1][tid] = 0u;
    else if (tid < 64) h1sh[1][tid - 32] = 0u;
    __syncthreads();

    ushort xcur = 0, xnxt = 0;
    if (isL0) xcur = xgb[0];

    for (int k = 0; k <= TT; ++k) {
        if (isL0 && k + 1 < TT) xnxt = xgb[(size_t)(k + 1) * 256];

        const bool active = isL0 ? (k < TT) : (k >= 1);
        if (active) {
            float a0 = 0.f, a1 = 0.f, a2 = 0.f, a3 = 0.f;
            if (isL0) {
                // h0(k) = lstm0(xg(k), h0(k-1))
                const uint4* hq = (const uint4*)&h0sh[(k + 1) & 1][0];
                uint4 v0, v1;
                v0 = hq[0]; v1 = hq[1]; D8(G0, v0, v1)
                v0 = hq[2]; v1 = hq[3]; D8(G1, v0, v1)
                v0 = hq[4]; v1 = hq[5]; D8(G2, v0, v1)
                v0 = hq[6]; v1 = hq[7]; D8(G3, v0, v1)
            } else {
                // h1(k-1) = lstm1(h0(k-1), h1(k-2))
                const uint4* aq = (const uint4*)&h0sh[(k + 1) & 1][0];
                const uint4* bq = (const uint4*)&h1sh[k & 1][0];
                uint4 v0, v1;
                v0 = aq[0]; v1 = aq[1]; D8(G0, v0, v1)
                v0 = aq[2]; v1 = aq[3]; D8(G1, v0, v1)
                v0 = aq[4]; v1 = aq[5]; D8(G2, v0, v1)
                v0 = aq[6]; v1 = aq[7]; D8(G3, v0, v1)
                v0 = bq[0]; v1 = bq[1]; D8(G4, v0, v1)
                v0 = bq[2]; v1 = bq[3]; D8(G5, v0, v1)
                v0 = bq[4]; v1 = bq[5]; D8(G6, v0, v1)
                v0 = bq[6]; v1 = bq[7]; D8(G7, v0, v1)
            }
            float pre = ((a0 + a1) + (a2 + a3)) + bias;
            if (isL0) pre += (float)__builtin_bit_cast(_Float16, xcur);
            float y   = __expf(nsc * pre);
            float rr  = __builtin_amdgcn_rcpf(y + 1.0f);
            float act = fmaf(aco, y, bco) * rr;
            // gather gates of own j across lanes l^16, l^32, l^48
            float s0 = act;
            float s1 = __shfl_xor(s0, 16, 64);
            float s2 = __shfl_xor(s0, 32, 64);
            float s3 = __shfl_xor(s1, 32, 64);
            const bool gb0 = (g & 1) != 0, gb1 = (g & 2) != 0;
            float pig = gb0 ? s1 * s3 : s0 * s2;                 // i * g
            float ff  = gb0 ? (gb1 ? s2 : s0) : (gb1 ? s3 : s1); // f
            float oo  = gb0 ? (gb1 ? s0 : s2) : (gb1 ? s1 : s3); // o
            cst = fmaf(ff, cst, pig);
            float y2 = __expf(2.0f * cst);
            float th = (y2 - 1.0f) * __builtin_amdgcn_rcpf(y2 + 1.0f);
            float hval = oo * th;
            if (g == 0) {
                _Float16 hf = (_Float16)hval;
                if (isL0) {
                    ((_Float16*)&h0sh[k & 1][0])[j] = hf;
                } else {
                    ((_Float16*)&h1sh[(k - 1) & 1][0])[j] = hf;
                    h1b[(size_t)(k - 1) * 64 + j] = __builtin_bit_cast(ushort, hf);
                }
            }
        }
        xcur = xnxt;
        __syncthreads();
    }
}

// ============ Kernel C: out[bt] = sigmoid(h1g[bt,:] . w_out + b_out) =========
__global__ __launch_bounds__(256)
void head_gemv(const ushort* __restrict__ h1g, const float* __restrict__ w_out,
               const float* __restrict__ b_out, float* __restrict__ outp)
{
    __shared__ float wsh[64];
    const int tid = threadIdx.x;
    if (tid < 64) wsh[tid] = w_out[tid];
    __syncthreads();
    const int bt = blockIdx.x * 256 + tid;
    const uint4* hp = (const uint4*)(h1g + (size_t)bt * 64);
    float s = 0.0f;
    #pragma unroll
    for (int i = 0; i < 8; ++i) {
        uint4 v = hp[i];
        const float* wp = &wsh[8 * i];
        h2 p;
        p = BC(v.x); s = fmaf((float)p[0], wp[0], s); s = fmaf((float)p[1], wp[1], s);
        p = BC(v.y); s = fmaf((float)p[0], wp[2], s); s = fmaf((float)p[1], wp[3], s);
        p = BC(v.z); s = fmaf((float)p[0], wp[4], s); s = fmaf((float)p[1], wp[5], s);
        p = BC(v.w); s = fmaf((float)p[0], wp[6], s); s = fmaf((float)p[1], wp[7], s);
    }
    outp[bt] = __builtin_amdgcn_rcpf(1.0f + __expf(-(s + b_out[0])));
}

extern "C" void kernel_launch(void* const* d_in, const int* in_sizes, int n_in,
                              void* d_out, int out_size, void* d_ws, size_t ws_size,
                              hipStream_t stream) {
    const float* x     = (const float*)d_in[0];
    const float* w_ih0 = (const float*)d_in[1];
    const float* w_hh0 = (const float*)d_in[2];
    const float* b_ih0 = (const float*)d_in[3];
    const float* b_hh0 = (const float*)d_in[4];
    const float* w_ih1 = (const float*)d_in[5];
    const float* w_hh1 = (const float*)d_in[6];
    const float* b_ih1 = (const float*)d_in[7];
    const float* b_hh1 = (const float*)d_in[8];
    const float* w_out = (const float*)d_in[9];
    const float* b_out = (const float*)d_in[10];
    float* out = (float*)d_out;

    ushort* xg  = (ushort*)d_ws;                                   // BT*256 f16 = 128 MiB
    ushort* h1g = (ushort*)((char*)d_ws + (size_t)BT * 256 * 2);   // BT*64  f16 =  32 MiB

    hipLaunchKernelGGL(xg_mfma, dim3(BT / 64), dim3(256), 0, stream, x, w_ih0, xg);
    hipLaunchKernelGGL(lstm2_core, dim3(BB), dim3(512), 0, stream,
                       w_hh0, b_ih0, b_hh0, w_ih1, w_hh1, b_ih1, b_hh1, xg, h1g);
    hipLaunchKernelGGL(head_gemv, dim3(BT / 256), dim3(256), 0, stream,
                       h1g, w_out, b_out, out);
}